// Round 11
// baseline (151.920 us; speedup 1.0000x reference)
//
#include <hip/hip_runtime.h>
#include <math.h>

// Whiten: per-(b,c) mean/std over 224x224 fp32 slices. B*C = 2048 slices.
// Floor: 411 MB read + 411 MB write @ ~6.3 TB/s ~= 131 us.
// R10 (phased + nontemporal both streams) = 140.1 us = 93% of copy ceiling.
//
// R11 = R8's persistent store/load-overlap structure + R10's nontemporal
// policy. Rationale: R8's 166 us regression was measured WITH L2 allocation,
// where interleaved read+write bursts thrash the 4 MB XCD L2; nt bypasses
// L2 entirely, and a plain copy kernel sustains concurrent read+write at
// 6.29 TB/s -- so the interleave penalty may have been pure L2 churn.
// Structure: 256 persistent blocks x 1024 thr, 8 slices each, fixed-role
// buffers (main 7+1 rows, pre 5 rows = 52 data VGPR, same as R1/R10).
// Per slice: acc -> butterfly -> raw lgkm-only barrier (prefetch loads stay
// in flight; wred parity-buffered) -> broadcast stats -> store main(s,nt);
// issue main(s+1,nt); store pre(s,nt); issue pre(s+1,nt). Next-slice reads
// stream through this slice's reduce + store window.
// Pre-committed read: <140 keep; >=145 revert to R10 and declare roofline.

namespace {
constexpr int   kHW       = 224 * 224;              // 50176
constexpr int   kHW4      = kHW / 4;                // 12544 float4 / slice
constexpr int   kThreads  = 1024;
constexpr int   kWaves    = kThreads / 64;          // 16
constexpr int   kPerBlock = 8;
constexpr int   kBlocks   = (64 * 32) / kPerBlock;  // 256
constexpr int   kPreRows  = 5;                      // rows 0..4 (full)
constexpr int   kMainRows = 7;                      // rows 5..11 (full)
constexpr int   kQOff     = 12 * kThreads;          // 12288, quarter row
constexpr int   kQCnt     = kHW4 - kQOff;           // 256 (tid<256)
constexpr float kMinDev   = 1.0f / 224.0f;          // 1/sqrt(H*W)

typedef float vfloat4 __attribute__((ext_vector_type(4)));
}

__global__ __launch_bounds__(kThreads, 4)   // cap 128 VGPR, 1 block/CU
void whiten_r11(const float* __restrict__ x, float* __restrict__ y) {
    __shared__ float2 wred[2][kWaves];      // parity-double-buffered stats

    const int  tid  = threadIdx.x;
    const int  wid  = tid >> 6;
    const int  lane = tid & 63;
    const bool q    = (tid < kQCnt);
    const size_t base = (size_t)blockIdx.x * kPerBlock * kHW4;
    const vfloat4* __restrict__ xs = reinterpret_cast<const vfloat4*>(x) + base;
    vfloat4* __restrict__ ys       = reinterpret_cast<vfloat4*>(y) + base;

    vfloat4 mn[kMainRows + 1];   // rows 5..11 + quarter row (32 VGPR)
    vfloat4 pre[kPreRows];       // rows 0..4                 (20 VGPR)

    auto issueMain = [&](int s) {
        const vfloat4* __restrict__ p = xs + (size_t)s * kHW4;
#pragma unroll
        for (int i = 0; i < kMainRows; ++i)
            mn[i] = __builtin_nontemporal_load(&p[(kPreRows + i) * kThreads + tid]);
        if (q) mn[kMainRows] = __builtin_nontemporal_load(&p[kQOff + tid]);
    };
    auto issuePre = [&](int s) {
        const vfloat4* __restrict__ p = xs + (size_t)s * kHW4;
#pragma unroll
        for (int i = 0; i < kPreRows; ++i)
            pre[i] = __builtin_nontemporal_load(&p[i * kThreads + tid]);
    };
    auto acc1 = [&](const vfloat4& v, float& sum, float& ssq) {
        sum += v.x + v.y + v.z + v.w;
        ssq = fmaf(v.x, v.x, ssq);
        ssq = fmaf(v.y, v.y, ssq);
        ssq = fmaf(v.z, v.z, ssq);
        ssq = fmaf(v.w, v.w, ssq);
    };
    auto norm1 = [&](const vfloat4& v, float mean, float rcp) {
        vfloat4 o;
        o.x = (v.x - mean) * rcp;
        o.y = (v.y - mean) * rcp;
        o.z = (v.z - mean) * rcp;
        o.w = (v.w - mean) * rcp;
        return o;
    };

    auto step = [&](int s, bool prefetchNext) {
        // ---- accumulate in ISSUE order (main first, then pre) ----
        float sum = 0.f, ssq = 0.f;
#pragma unroll
        for (int i = 0; i < kMainRows; ++i) acc1(mn[i], sum, ssq);
        if (q) acc1(mn[kMainRows], sum, ssq);
#pragma unroll
        for (int i = 0; i < kPreRows; ++i) acc1(pre[i], sum, ssq);

        // ---- wave64 butterfly ----
#pragma unroll
        for (int off = 32; off >= 1; off >>= 1) {
            sum += __shfl_xor(sum, off, 64);
            ssq += __shfl_xor(ssq, off, 64);
        }
        if (lane == 0) wred[s & 1][wid] = make_float2(sum, ssq);
        // LDS-only barrier: never drain vmcnt in the loop.
        asm volatile("s_waitcnt lgkmcnt(0)\n\ts_barrier" ::: "memory");

        // ---- broadcast stats (all threads reduce 16 entries) ----
        float S = 0.f, SS = 0.f;
#pragma unroll
        for (int i = 0; i < kWaves; ++i) {
            S += wred[s & 1][i].x;
            SS += wred[s & 1][i].y;
        }
        const float mean = S * (1.0f / kHW);
        float var = (SS - S * mean) * (1.0f / (kHW - 1));
        var = fmaxf(var, 0.f);
        const float rcp = 1.0f / fmaxf(sqrtf(var), kMinDev);

        // ---- store main(s); refill main with slice s+1 ----
        vfloat4* __restrict__ p = ys + (size_t)s * kHW4;
#pragma unroll
        for (int i = 0; i < kMainRows; ++i)
            __builtin_nontemporal_store(norm1(mn[i], mean, rcp),
                                        &p[(kPreRows + i) * kThreads + tid]);
        if (q) __builtin_nontemporal_store(norm1(mn[kMainRows], mean, rcp),
                                           &p[kQOff + tid]);
        if (prefetchNext) issueMain(s + 1);   // reads stream during store win
        // ---- store pre(s); refill pre with slice s+1 ----
#pragma unroll
        for (int i = 0; i < kPreRows; ++i)
            __builtin_nontemporal_store(norm1(pre[i], mean, rcp),
                                        &p[i * kThreads + tid]);
        if (prefetchNext) issuePre(s + 1);
    };

    // prologue: issue order main-then-pre (matches steady state)
    issueMain(0);
    issuePre(0);
#pragma unroll 1
    for (int s = 0; s < kPerBlock - 1; ++s) step(s, true);
    step(kPerBlock - 1, false);
}

extern "C" void kernel_launch(void* const* d_in, const int* in_sizes, int n_in,
                              void* d_out, int out_size, void* d_ws, size_t ws_size,
                              hipStream_t stream) {
    (void)in_sizes; (void)n_in; (void)d_ws; (void)ws_size; (void)out_size;
    const float* x = reinterpret_cast<const float*>(d_in[0]);
    float* y = reinterpret_cast<float*>(d_out);
    whiten_r11<<<kBlocks, kThreads, 0, stream>>>(x, y);
}

// Round 12
// 140.042 us; speedup vs baseline: 1.0848x; 1.0848x over previous
//
#include <hip/hip_runtime.h>
#include <math.h>

// Whiten: per-(b,c) mean/std over 224x224 fp32 slices. B*C = 2048 slices.
// Floor: 411 MB read + 411 MB write @ ~6.3 TB/s ~= 131 us.
//
// R12 = R10 restored (best: 140.1 us = 93% of the 6.29 TB/s copy ceiling).
// Final structure: phased read-all -> reduce -> write-all; one-shot
// 1024-thread block per slice; 13 float4 staged in registers; BOTH streams
// nontemporal (stream-once data: L2/L3 allocation is pure churn -- removing
// it was worth 16.5 us). Overlap/pipelining/co-residency all measured
// worse, with and without nt (R2,R5,R6,R7,R8,R11): phase-separated bursts
// sustain ~5.87 TB/s vs ~5.4 TB/s interleaved on this access pattern.
// Remaining ~7%: per-round phase-tail (last-load latency + reduce + retire
// at 1 block/CU) -- structural, five attempts to recover it all regressed.

namespace {
constexpr int kHW      = 224 * 224;                 // 50176
constexpr int kHW4     = kHW / 4;                   // 12544 float4 / slice
constexpr int kThreads = 1024;
constexpr int kIt      = kHW4 / kThreads;           // 12
constexpr int kExtra   = kHW4 - kIt * kThreads;     // 256 tail float4
constexpr int kSlices  = 64 * 32;                   // 2048
constexpr int kWaves   = kThreads / 64;             // 16
constexpr float kMinDev = 1.0f / 224.0f;            // 1/sqrt(H*W)

typedef float vfloat4 __attribute__((ext_vector_type(4)));
}

__global__ __launch_bounds__(kThreads, 1)
void whiten_r12(const float* __restrict__ x, float* __restrict__ y) {
    __shared__ float2 wred[kWaves];

    const int tid  = threadIdx.x;
    const int wid  = tid >> 6;
    const int lane = tid & 63;
    const bool extra = (tid < kExtra);
    const size_t base = (size_t)blockIdx.x * kHW4;
    const vfloat4* __restrict__ xs = reinterpret_cast<const vfloat4*>(x) + base;
    vfloat4* __restrict__ ys       = reinterpret_cast<vfloat4*>(y) + base;

    // ---- phase 1: read entire slice into registers (nontemporal) ----
    vfloat4 v[kIt];
    vfloat4 ve = {0.f, 0.f, 0.f, 0.f};
#pragma unroll
    for (int i = 0; i < kIt; ++i)
        v[i] = __builtin_nontemporal_load(&xs[tid + i * kThreads]);
    if (extra) ve = __builtin_nontemporal_load(&xs[kIt * kThreads + tid]);

    // ---- per-thread partials, 2-way split chains ----
    float s0 = 0.f, s1 = 0.f, q0 = 0.f, q1 = 0.f;
#pragma unroll
    for (int i = 0; i < kIt; ++i) {
        s0 += v[i].x + v[i].y;
        s1 += v[i].z + v[i].w;
        q0 = fmaf(v[i].x, v[i].x, q0);
        q1 = fmaf(v[i].y, v[i].y, q1);
        q0 = fmaf(v[i].z, v[i].z, q0);
        q1 = fmaf(v[i].w, v[i].w, q1);
    }
    s0 += ve.x + ve.y;
    s1 += ve.z + ve.w;
    q0 = fmaf(ve.x, ve.x, q0);
    q1 = fmaf(ve.y, ve.y, q1);
    q0 = fmaf(ve.z, ve.z, q0);
    q1 = fmaf(ve.w, ve.w, q1);
    float sum = s0 + s1;
    float ssq = q0 + q1;

    // ---- wave64 xor-butterfly ----
#pragma unroll
    for (int off = 32; off >= 1; off >>= 1) {
        sum += __shfl_xor(sum, off, 64);
        ssq += __shfl_xor(ssq, off, 64);
    }
    if (lane == 0) wred[wid] = make_float2(sum, ssq);
    __syncthreads();   // single barrier; vmcnt already 0 (loads consumed)

    // ---- all threads broadcast-reduce the 16 wave entries ----
    float S = 0.f, SS = 0.f;
#pragma unroll
    for (int i = 0; i < kWaves; ++i) { S += wred[i].x; SS += wred[i].y; }
    const float mean = S * (1.0f / kHW);
    float var = (SS - S * mean) * (1.0f / (kHW - 1));
    var = fmaxf(var, 0.f);
    const float rcp = 1.0f / fmaxf(sqrtf(var), kMinDev);

    // ---- phase 2: normalize + store from registers (nontemporal) ----
#pragma unroll
    for (int i = 0; i < kIt; ++i) {
        vfloat4 o;
        o.x = (v[i].x - mean) * rcp;
        o.y = (v[i].y - mean) * rcp;
        o.z = (v[i].z - mean) * rcp;
        o.w = (v[i].w - mean) * rcp;
        __builtin_nontemporal_store(o, &ys[tid + i * kThreads]);
    }
    if (extra) {
        vfloat4 o;
        o.x = (ve.x - mean) * rcp;
        o.y = (ve.y - mean) * rcp;
        o.z = (ve.z - mean) * rcp;
        o.w = (ve.w - mean) * rcp;
        __builtin_nontemporal_store(o, &ys[kIt * kThreads + tid]);
    }
}

extern "C" void kernel_launch(void* const* d_in, const int* in_sizes, int n_in,
                              void* d_out, int out_size, void* d_ws, size_t ws_size,
                              hipStream_t stream) {
    (void)in_sizes; (void)n_in; (void)d_ws; (void)ws_size; (void)out_size;
    const float* x = reinterpret_cast<const float*>(d_in[0]);
    float* y = reinterpret_cast<float*>(d_out);
    whiten_r12<<<kSlices, kThreads, 0, stream>>>(x, y);
}